// Round 1
// baseline (152.244 us; speedup 1.0000x reference)
//
#include <hip/hip_runtime.h>

// KeySegPred — baseline fp32 implementation.
// Kernel A (mlp_kernel): code = [emb_feat[src] | emb_dest[dest] | offset[:,1:3]]
//   h = relu(BN(code @ w1.T + b1)); out = h @ w2.T + b2  -> d_ws (4096x256 f32)
// Kernel B (logits_kernel): per (b, m) candidate:
//   logits[b,m] = dot(dense_w[cand], out[b,0:252]) + dot(emb_cand, out[b,252:256]) + dense_b[cand]
//   emb_cand from [cos_feat, traffic_feat] @ cand_w.T + cand_b

#define BATCH 4096
#define DSEG 128
#define DS_ 258
#define DM7 512
#define DM8 256
#define NCAND 64
#define DWC 252
#define TSLOTS 96
#define TROWS 8

__global__ __launch_bounds__(256) void mlp_kernel(
    const int* __restrict__ src, const int* __restrict__ dest,
    const float* __restrict__ offset,
    const float* __restrict__ emb_feat, const float* __restrict__ emb_dest,
    const float* __restrict__ w1, const float* __restrict__ b1,
    const float* __restrict__ bn_gamma, const float* __restrict__ bn_beta,
    const float* __restrict__ bn_mean, const float* __restrict__ bn_var,
    const float* __restrict__ w2, const float* __restrict__ b2,
    float* __restrict__ out_ws)
{
    __shared__ float code[TROWS][260];   // 258 used, row stride 1040B (16B aligned)
    __shared__ float hbuf[TROWS][516];   // 512 used, row stride 2064B (16B aligned)
    const int tid = threadIdx.x;
    const int b0 = blockIdx.x * TROWS;

    // ---- stage code tile: 8 rows x (128 + 128 + 2) ----
    {
        const int r = tid >> 5;   // 0..7
        const int i = tid & 31;   // 0..31
        const int bs = src[b0 + r];
        const int bd = dest[b0 + r];
        float4 v = *(const float4*)(emb_feat + (size_t)bs * DSEG + i * 4);
        *(float4*)&code[r][i * 4] = v;
        v = *(const float4*)(emb_dest + (size_t)bd * DSEG + i * 4);
        *(float4*)&code[r][128 + i * 4] = v;
        if (i == 0) {
            code[r][256] = offset[(b0 + r) * 4 + 1];
            code[r][257] = offset[(b0 + r) * 4 + 2];
        }
    }
    __syncthreads();

    // ---- MLP1: each thread owns cols c0=tid and c1=tid+256, 8 batch rows ----
    const int c0 = tid;
    const int c1 = tid + 256;
    float acc0[TROWS], acc1[TROWS];
#pragma unroll
    for (int r = 0; r < TROWS; ++r) { acc0[r] = 0.f; acc1[r] = 0.f; }
    // w1 rows are 258 floats = 1032B -> only 8B aligned, use float2
    const float2* __restrict__ w1a = (const float2*)(w1 + c0 * DS_);
    const float2* __restrict__ w1b = (const float2*)(w1 + c1 * DS_);
    for (int k2 = 0; k2 < DS_ / 2; ++k2) {
        const float2 wa = w1a[k2];
        const float2 wb = w1b[k2];
#pragma unroll
        for (int r = 0; r < TROWS; ++r) {
            const float2 cv = *(const float2*)&code[r][k2 * 2];  // LDS broadcast
            acc0[r] = fmaf(wa.x, cv.x, acc0[r]);
            acc0[r] = fmaf(wa.y, cv.y, acc0[r]);
            acc1[r] = fmaf(wb.x, cv.x, acc1[r]);
            acc1[r] = fmaf(wb.y, cv.y, acc1[r]);
        }
    }
    // ---- BN + ReLU -> hbuf ----
    {
        const float s0 = bn_gamma[c0] / sqrtf(bn_var[c0] + 1e-6f);
        const float s1 = bn_gamma[c1] / sqrtf(bn_var[c1] + 1e-6f);
        const float m0 = bn_mean[c0], m1 = bn_mean[c1];
        const float be0 = bn_beta[c0], be1 = bn_beta[c1];
        const float bb0 = b1[c0], bb1 = b1[c1];
#pragma unroll
        for (int r = 0; r < TROWS; ++r) {
            const float h0 = (acc0[r] + bb0 - m0) * s0 + be0;
            const float h1 = (acc1[r] + bb1 - m1) * s1 + be1;
            hbuf[r][c0] = fmaxf(h0, 0.f);
            hbuf[r][c1] = fmaxf(h1, 0.f);
        }
    }
    __syncthreads();

    // ---- MLP2: each thread owns out-col c0 (0..255), 8 batch rows ----
    float acc2[TROWS];
#pragma unroll
    for (int r = 0; r < TROWS; ++r) acc2[r] = 0.f;
    const float4* __restrict__ w2v = (const float4*)(w2 + c0 * DM7);  // 2048B rows, 16B aligned
    for (int k4 = 0; k4 < DM7 / 4; ++k4) {
        const float4 wv = w2v[k4];
#pragma unroll
        for (int r = 0; r < TROWS; ++r) {
            const float4 hv = *(const float4*)&hbuf[r][k4 * 4];  // LDS broadcast
            acc2[r] = fmaf(wv.x, hv.x, acc2[r]);
            acc2[r] = fmaf(wv.y, hv.y, acc2[r]);
            acc2[r] = fmaf(wv.z, hv.z, acc2[r]);
            acc2[r] = fmaf(wv.w, hv.w, acc2[r]);
        }
    }
    const float bo = b2[c0];
#pragma unroll
    for (int r = 0; r < TROWS; ++r) {
        out_ws[(size_t)(b0 + r) * DM8 + c0] = acc2[r] + bo;  // coalesced
    }
}

__global__ __launch_bounds__(256) void logits_kernel(
    const int* __restrict__ dest, const int* __restrict__ tt,
    const int* __restrict__ candidates,
    const float* __restrict__ dense_w, const float* __restrict__ dense_b,
    const float* __restrict__ cand_w, const float* __restrict__ cand_b,
    const float* __restrict__ segs_src, const float* __restrict__ segs_trg,
    const float* __restrict__ traffic_pop,
    const float* __restrict__ out_ws,
    float* __restrict__ logits)
{
    const int b = blockIdx.x;
    const int tid = threadIdx.x;
    const int wave = tid >> 6;
    const int lane = tid & 63;

    // lane l holds out[b, 4l..4l+3]; lane 63's fragment is out[252..256) = emb_cand slot
    const float4 o4 = *(const float4*)(out_ws + (size_t)b * DM8 + lane * 4);
    const int db = dest[b];
    const float2 dsx = *(const float2*)(segs_src + 2 * (size_t)db);
    const int tb = tt[b];
    float cw[8], cb4[4];
#pragma unroll
    for (int j = 0; j < 8; ++j) cw[j] = cand_w[j];
#pragma unroll
    for (int j = 0; j < 4; ++j) cb4[j] = cand_b[j];

    const int mbase = wave * 16;  // 4 waves x 16 candidates = 64
    for (int mi = 0; mi < 16; ++mi) {
        const int m = mbase + mi;
        const int cand = candidates[b * NCAND + m];
        float p;
        if (lane < 63) {
            // dense_w rows: 252 floats = 1008B, 16B aligned -> one float4/lane
            const float4 dw = *(const float4*)(dense_w + (size_t)cand * DWC + lane * 4);
            p = dw.x * o4.x + dw.y * o4.y + dw.z * o4.z + dw.w * o4.w;
        } else {
            // lane 63: candidate-feature tail  emb_cand . out[252:256]
            const float2 sx = *(const float2*)(segs_src + 2 * (size_t)cand);
            const float2 tx = *(const float2*)(segs_trg + 2 * (size_t)cand);
            const float v1x = dsx.x - sx.x, v1y = dsx.y - sx.y;
            const float v2x = tx.x - sx.x, v2y = tx.y - sx.y;
            const float num = v1x * v2x + v1y * v2y;
            const float den = fmaxf(sqrtf(v1x * v1x + v1y * v1y) *
                                    sqrtf(v2x * v2x + v2y * v2y), 1e-8f);
            const float cosv = num / den;
            const float tf = traffic_pop[(size_t)cand * TSLOTS + tb];
            const float e0 = fmaf(cosv, cw[0], fmaf(tf, cw[1], cb4[0]));
            const float e1 = fmaf(cosv, cw[2], fmaf(tf, cw[3], cb4[1]));
            const float e2 = fmaf(cosv, cw[4], fmaf(tf, cw[5], cb4[2]));
            const float e3 = fmaf(cosv, cw[6], fmaf(tf, cw[7], cb4[3]));
            p = e0 * o4.x + e1 * o4.y + e2 * o4.z + e3 * o4.w;
        }
        // 64-lane butterfly reduce
#pragma unroll
        for (int s = 1; s < 64; s <<= 1) p += __shfl_xor(p, s, 64);
        if (lane == 0) logits[(size_t)b * NCAND + m] = p + dense_b[cand];
    }
}

extern "C" void kernel_launch(void* const* d_in, const int* in_sizes, int n_in,
                              void* d_out, int out_size, void* d_ws, size_t ws_size,
                              hipStream_t stream) {
    const int*   src         = (const int*)d_in[0];
    const int*   dest        = (const int*)d_in[1];
    const int*   tt          = (const int*)d_in[2];
    const int*   candidates  = (const int*)d_in[3];
    const float* offset      = (const float*)d_in[4];
    const float* emb_feat    = (const float*)d_in[5];
    const float* emb_dest    = (const float*)d_in[6];
    const float* w1          = (const float*)d_in[7];
    const float* b1          = (const float*)d_in[8];
    const float* bn_gamma    = (const float*)d_in[9];
    const float* bn_beta     = (const float*)d_in[10];
    const float* bn_mean     = (const float*)d_in[11];
    const float* bn_var      = (const float*)d_in[12];
    const float* w2          = (const float*)d_in[13];
    const float* b2          = (const float*)d_in[14];
    const float* dense_w     = (const float*)d_in[15];
    const float* dense_b     = (const float*)d_in[16];
    const float* cand_w      = (const float*)d_in[17];
    const float* cand_b      = (const float*)d_in[18];
    const float* segs_src    = (const float*)d_in[19];
    const float* segs_trg    = (const float*)d_in[20];
    const float* traffic_pop = (const float*)d_in[21];

    float* out_ws = (float*)d_ws;           // 4096*256 f32 = 4 MB scratch
    float* logits = (float*)d_out;          // 4096*64 f32

    mlp_kernel<<<BATCH / TROWS, 256, 0, stream>>>(
        src, dest, offset, emb_feat, emb_dest,
        w1, b1, bn_gamma, bn_beta, bn_mean, bn_var, w2, b2, out_ws);

    logits_kernel<<<BATCH, 256, 0, stream>>>(
        dest, tt, candidates, dense_w, dense_b, cand_w, cand_b,
        segs_src, segs_trg, traffic_pop, out_ws, logits);
}